// Round 12
// baseline (599.499 us; speedup 1.0000x reference)
//
#include <hip/hip_runtime.h>

typedef float v4f __attribute__((ext_vector_type(4)));

#define N_NODES_C 50000
#define N_EDGES_C 800000
#define NF 128
#define N_GRAPHS_C 256
#define N_CLASSES_C 10

#define SCAN_CHUNK 512
#define SCAN_NB ((N_NODES_C + SCAN_CHUNK - 1) / SCAN_CHUNK)   // 98

// ---------------------------------------------------------------- CSR build
__global__ void k_deg(const int* __restrict__ dst, int* __restrict__ deg) {
  int i = blockIdx.x * blockDim.x + threadIdx.x;
  int stride = gridDim.x * blockDim.x;
  for (; i < N_EDGES_C; i += stride) atomicAdd(&deg[dst[i]], 1);
}

__global__ __launch_bounds__(256) void k_sc1(const int* __restrict__ deg,
                                             float* __restrict__ dinv,
                                             int* __restrict__ bsum) {
  __shared__ int sd[256];
  int b = blockIdx.x, t = threadIdx.x;
  int i0 = b * SCAN_CHUNK + t * 2;
  int e0 = 0, e1 = 0;
  if (i0 < N_NODES_C)     { e0 = deg[i0];     dinv[i0]     = rsqrtf((float)e0 + 1.0f); }
  if (i0 + 1 < N_NODES_C) { e1 = deg[i0 + 1]; dinv[i0 + 1] = rsqrtf((float)e1 + 1.0f); }
  sd[t] = e0 + e1;
  __syncthreads();
  for (int o = 128; o > 0; o >>= 1) {
    if (t < o) sd[t] += sd[t + o];
    __syncthreads();
  }
  if (t == 0) bsum[b] = sd[0];
}

__global__ __launch_bounds__(128) void k_sc2(const int* __restrict__ bsum,
                                             int* __restrict__ boff,
                                             int* __restrict__ ptr) {
  __shared__ int sd[128];
  int t = threadIdx.x;
  int v = (t < SCAN_NB) ? bsum[t] : 0;
  sd[t] = v;
  __syncthreads();
  for (int o = 1; o < 128; o <<= 1) {
    int y = (t >= o) ? sd[t - o] : 0;
    __syncthreads();
    sd[t] += y;
    __syncthreads();
  }
  if (t < SCAN_NB) boff[t] = sd[t] - v;
  if (t == SCAN_NB - 1) ptr[N_NODES_C] = sd[t];
}

__global__ __launch_bounds__(256) void k_sc3(const int* __restrict__ deg,
                                             const int* __restrict__ boff,
                                             int* __restrict__ ptr) {
  __shared__ int sd[256];
  int b = blockIdx.x, t = threadIdx.x;
  int i0 = b * SCAN_CHUNK + t * 2;
  int e0 = (i0 < N_NODES_C) ? deg[i0] : 0;
  int e1 = (i0 + 1 < N_NODES_C) ? deg[i0 + 1] : 0;
  int pair = e0 + e1;
  sd[t] = pair;
  __syncthreads();
  for (int o = 1; o < 256; o <<= 1) {
    int y = (t >= o) ? sd[t - o] : 0;
    __syncthreads();
    sd[t] += y;
    __syncthreads();
  }
  int excl = boff[b] + sd[t] - pair;
  if (i0 < N_NODES_C)     ptr[i0] = excl;
  if (i0 + 1 < N_NODES_C) ptr[i0 + 1] = excl + e0;
}

__global__ void k_fill(const int* __restrict__ src, const int* __restrict__ dst,
                       const int* __restrict__ ptr, int* __restrict__ fill,
                       int* __restrict__ csr_src) {
  int i = blockIdx.x * blockDim.x + threadIdx.x;
  int stride = gridDim.x * blockDim.x;
  for (; i < N_EDGES_C; i += stride) {
    int d = dst[i];
    int pos = atomicAdd(&fill[d], 1);
    csr_src[ptr[d] + pos] = src[i];
  }
}

// ---------------------------------------------------------------- GEMM (fp32, 8x8 register blocking)
// Tile 128x128, 256 threads, thread = 8 rows x 8 cols (64 acc).
// W (full 128x128) resident in LDS, plain layout (reads broadcast over rg,
// 4 distinct bank-quads over cg -> conflict-free). Staged ONCE per block.
// H swizzled: slot = (c4 + (row>>3)) & 31 -> 16-lane row-gather reads are
// 2-way (free); plain padding cannot fix (8*rowstride = 0 mod 32 banks).
// Per k4: 16 LDS b128 (~64 cy) vs 256 VALU cy -> VALU-bound.
// mode 0: A@W   mode 1: relu(A@W+bias)   mode 2: (A@W)*dinv[row]
#define TM 128
__global__ __launch_bounds__(256, 1) void k_gemm(const float* __restrict__ A,
    const float* __restrict__ W, const float* __restrict__ bias,
    const float* __restrict__ dinv, float* __restrict__ out, int n, int mode) {
  __shared__ v4f Hl[TM * 33];     // 67584 B, swizzled
  __shared__ v4f Wl[128 * 32];    // 65536 B, plain
  int t = threadIdx.x;
  int rg = t & 15;                // rows rg*8 .. rg*8+7
  int cg = t >> 4;                // cols cg*8 .. cg*8+7   (cg 0..15)
  const v4f* W4 = (const v4f*)W;
  #pragma unroll
  for (int i = 0; i < 16; ++i) Wl[t + i * 256] = W4[t + i * 256];

  int nchunks = (n + TM - 1) / TM;
  for (int chunk = blockIdx.x; chunk < nchunks; chunk += gridDim.x) {
    int n0 = chunk * TM;
    __syncthreads();              // Hl safe to overwrite; also fences Wl stage on first iter
    {
      const v4f* A4 = (const v4f*)A;
      #pragma unroll
      for (int i = 0; i < 16; ++i) {
        int idx = t + i * 256;                // 0..4095
        int row = idx >> 5, c4 = idx & 31;
        Hl[row * 33 + ((c4 + (row >> 3)) & 31)] =
            (n0 + row < n) ? A4[(size_t)(n0 + row) * 32 + c4] : (v4f)0.0f;
      }
    }
    __syncthreads();
    v4f acc0[8], acc1[8];
    #pragma unroll
    for (int j = 0; j < 8; ++j) { acc0[j] = (v4f)0.0f; acc1[j] = (v4f)0.0f; }
    #pragma unroll 2
    for (int k4 = 0; k4 < 32; ++k4) {
      int slot = (k4 + rg) & 31;              // (row>>3)==rg for all 8 rows
      v4f hv[8];
      #pragma unroll
      for (int j = 0; j < 8; ++j) hv[j] = Hl[(rg * 8 + j) * 33 + slot];
      #pragma unroll
      for (int kk = 0; kk < 4; ++kk) {
        v4f w0 = Wl[(k4 * 4 + kk) * 32 + cg * 2];
        v4f w1 = Wl[(k4 * 4 + kk) * 32 + cg * 2 + 1];
        #pragma unroll
        for (int j = 0; j < 8; ++j) {
          acc0[j] += hv[j][kk] * w0;
          acc1[j] += hv[j][kk] * w1;
        }
      }
    }
    v4f b0 = (v4f)0.0f, b1 = (v4f)0.0f;
    if (mode == 1) { b0 = ((const v4f*)bias)[cg * 2]; b1 = ((const v4f*)bias)[cg * 2 + 1]; }
    #pragma unroll
    for (int j = 0; j < 8; ++j) {
      int row = n0 + rg * 8 + j;
      if (row < n) {
        v4f r0 = acc0[j], r1 = acc1[j];
        if (mode == 1) {
          r0 += b0; r1 += b1;
          #pragma unroll
          for (int c = 0; c < 4; ++c) { r0[c] = fmaxf(r0[c], 0.0f); r1[c] = fmaxf(r1[c], 0.0f); }
        } else if (mode == 2) {
          float dv = dinv[row];
          r0 *= dv; r1 *= dv;
        }
        *(v4f*)(out + (size_t)row * 128 + cg * 8) = r0;
        *(v4f*)(out + (size_t)row * 128 + cg * 8 + 4) = r1;
      }
    }
  }
}

// ---------------------------------------------------------------- aggregation
// hws = dinv-pre-scaled hw'. h_i = relu(dinv_i*(sum_{j->i} hw'_j + hw'_i) + b) [+h_i]
// At the fp32 random-gather floor: FETCH ~= 8 XCD x 25.6 MB compulsory, ~3.7 TB/s.
__global__ __launch_bounds__(256) void k_agg(const float* __restrict__ hws,
    const int* __restrict__ ptr, const int* __restrict__ csr_src,
    const float* __restrict__ dinv, const float* __restrict__ bias,
    float* __restrict__ h, int residual) {
  int node = blockIdx.x * 4 + (threadIdx.x >> 6);
  int lane = threadIdx.x & 63;
  int half = lane >> 5;
  int c4 = lane & 31;
  if (node >= N_NODES_C) return;
  const v4f* hw4 = (const v4f*)hws;
  int beg = ptr[node], end = ptr[node + 1];
  v4f acc = (v4f)0.0f;
  int e = beg;
  for (; e + 16 <= end; e += 16) {
    int s0 = csr_src[e +  0 + half], s1 = csr_src[e +  2 + half];
    int s2 = csr_src[e +  4 + half], s3 = csr_src[e +  6 + half];
    int s4 = csr_src[e +  8 + half], s5 = csr_src[e + 10 + half];
    int s6 = csr_src[e + 12 + half], s7 = csr_src[e + 14 + half];
    v4f v0 = hw4[(size_t)s0 * 32 + c4];
    v4f v1 = hw4[(size_t)s1 * 32 + c4];
    v4f v2 = hw4[(size_t)s2 * 32 + c4];
    v4f v3 = hw4[(size_t)s3 * 32 + c4];
    v4f v4 = hw4[(size_t)s4 * 32 + c4];
    v4f v5 = hw4[(size_t)s5 * 32 + c4];
    v4f v6 = hw4[(size_t)s6 * 32 + c4];
    v4f v7 = hw4[(size_t)s7 * 32 + c4];
    acc += v0; acc += v1; acc += v2; acc += v3;
    acc += v4; acc += v5; acc += v6; acc += v7;
  }
  for (; e + 8 <= end; e += 8) {
    int s0 = csr_src[e + half],     s1 = csr_src[e + 2 + half];
    int s2 = csr_src[e + 4 + half], s3 = csr_src[e + 6 + half];
    v4f v0 = hw4[(size_t)s0 * 32 + c4];
    v4f v1 = hw4[(size_t)s1 * 32 + c4];
    v4f v2 = hw4[(size_t)s2 * 32 + c4];
    v4f v3 = hw4[(size_t)s3 * 32 + c4];
    acc += v0; acc += v1; acc += v2; acc += v3;
  }
  for (; e < end; e += 2) {
    int idx = e + half;
    if (idx < end) acc += hw4[(size_t)csr_src[idx] * 32 + c4];
  }
  v4f tot;
  #pragma unroll
  for (int c = 0; c < 4; ++c) tot[c] = acc[c] + __shfl_xor(acc[c], 32);

  float di = dinv[node];
  v4f selfv = hw4[(size_t)node * 32 + c4];
  v4f b = ((const v4f*)bias)[c4];
  v4f r = di * (tot + selfv) + b;
  #pragma unroll
  for (int c = 0; c < 4; ++c) r[c] = fmaxf(r[c], 0.0f);
  v4f* h4 = (v4f*)h;
  if (residual) r += h4[(size_t)node * 32 + c4];
  if (half == 0) h4[(size_t)node * 32 + c4] = r;
}

// ---------------------------------------------------------------- pooling + head
__global__ void k_bounds(const int* __restrict__ batch, int* __restrict__ gstart) {
  int g = threadIdx.x;
  if (g > N_GRAPHS_C) return;
  int lo = 0, hi = N_NODES_C;
  while (lo < hi) {
    int mid = (lo + hi) >> 1;
    if (batch[mid] < g) lo = mid + 1; else hi = mid;
  }
  gstart[g] = lo;
}

__global__ void k_pool(const float* __restrict__ h, const int* __restrict__ gstart,
                       float* __restrict__ gpool) {
  int g = blockIdx.x;
  int f = threadIdx.x;
  int beg = gstart[g], end = gstart[g + 1];
  float acc = 0.f;
  for (int n2 = beg; n2 < end; ++n2) acc += h[(size_t)n2 * NF + f];
  float cnt = (float)(end - beg);
  gpool[g * NF + f] = acc / fmaxf(cnt, 1.0f);
}

__global__ void k_head(const float* __restrict__ gpool, const float* __restrict__ Wc1,
                       const float* __restrict__ bc1, const float* __restrict__ Wc2,
                       const float* __restrict__ bc2, float* __restrict__ out) {
  __shared__ float gv[128];
  __shared__ float hid[64];
  int g = blockIdx.x, t = threadIdx.x;
  gv[t] = gpool[g * 128 + t];
  gv[t + 64] = gpool[g * 128 + t + 64];
  __syncthreads();
  float s = bc1[t];
  #pragma unroll 8
  for (int k = 0; k < 128; ++k) s += gv[k] * Wc1[k * 64 + t];
  hid[t] = fmaxf(s, 0.0f);
  __syncthreads();
  if (t < N_CLASSES_C) {
    float o = bc2[t];
    #pragma unroll
    for (int k = 0; k < 64; ++k) o += hid[k] * Wc2[k * 10 + t];
    out[g * 10 + t] = o;
  }
}

// ---------------------------------------------------------------- launch
extern "C" void kernel_launch(void* const* d_in, const int* in_sizes, int n_in,
                              void* d_out, int out_size, void* d_ws, size_t ws_size,
                              hipStream_t stream) {
  const float* x    = (const float*)d_in[0];
  const int*   ei   = (const int*)d_in[1];
  const int*   batch= (const int*)d_in[2];
  const float* W_in = (const float*)d_in[3];
  const float* b_in = (const float*)d_in[4];
  const float* Ws   = (const float*)d_in[5];
  const float* bs   = (const float*)d_in[6];
  const float* Wc1  = (const float*)d_in[7];
  const float* bc1  = (const float*)d_in[8];
  const float* Wc2  = (const float*)d_in[9];
  const float* bc2  = (const float*)d_in[10];
  float* out = (float*)d_out;

  const int* src = ei;
  const int* dst = ei + N_EDGES_C;

  char* ws = (char*)d_ws;
  size_t off = 0;
  auto alloc = [&](size_t bytes) -> void* {
    void* p = ws + off;
    off += (bytes + 255) & ~(size_t)255;
    return p;
  };
  int*   deg     = (int*)alloc(N_NODES_C * 4);
  int*   fill    = (int*)alloc(N_NODES_C * 4);
  int*   csr_ptr = (int*)alloc((N_NODES_C + 1) * 4);
  int*   csr_src = (int*)alloc((size_t)N_EDGES_C * 4);
  float* dinv    = (float*)alloc(N_NODES_C * 4);
  int*   gstart  = (int*)alloc((N_GRAPHS_C + 1) * 4);
  int*   bsum    = (int*)alloc(SCAN_NB * 4);
  int*   boff    = (int*)alloc(SCAN_NB * 4);
  float* h       = (float*)alloc((size_t)N_NODES_C * NF * 4);
  float* hw      = (float*)alloc((size_t)N_NODES_C * NF * 4);
  float* gpool   = (float*)alloc((size_t)N_GRAPHS_C * NF * 4);
  (void)ws_size; (void)in_sizes; (void)n_in; (void)out_size;

  hipMemsetAsync(deg, 0, N_NODES_C * 4, stream);
  hipMemsetAsync(fill, 0, N_NODES_C * 4, stream);

  k_deg<<<1024, 256, 0, stream>>>(dst, deg);
  k_sc1<<<SCAN_NB, 256, 0, stream>>>(deg, dinv, bsum);
  k_sc2<<<1, 128, 0, stream>>>(bsum, boff, csr_ptr);
  k_sc3<<<SCAN_NB, 256, 0, stream>>>(deg, boff, csr_ptr);
  k_fill<<<1024, 256, 0, stream>>>(src, dst, csr_ptr, fill, csr_src);

  const int GRID_GEMM = (N_NODES_C + TM - 1) / TM;   // 391

  // input layer: h = relu(x @ W_in + b_in)
  k_gemm<<<GRID_GEMM, 256, 0, stream>>>(x, W_in, b_in, nullptr, h, N_NODES_C, 1);

  for (int L = 0; L < 3; ++L) {
    // hw' = (h @ Ws[L]) * dinv  (pre-scaled for aggregation)
    k_gemm<<<GRID_GEMM, 256, 0, stream>>>(h, Ws + (size_t)L * NF * NF, nullptr, dinv,
                                          hw, N_NODES_C, 2);
    k_agg <<<(N_NODES_C + 3) / 4, 256, 0, stream>>>(hw, csr_ptr, csr_src, dinv,
                                                    bs + (size_t)L * NF, h, (L > 0) ? 1 : 0);
  }

  k_bounds<<<1, 512, 0, stream>>>(batch, gstart);
  k_pool  <<<N_GRAPHS_C, 128, 0, stream>>>(h, gstart, gpool);
  k_head  <<<N_GRAPHS_C, 64, 0, stream>>>(gpool, Wc1, bc1, Wc2, bc2, out);
}

// Round 15
// 568.218 us; speedup vs baseline: 1.0551x; 1.0551x over previous
//
#include <hip/hip_runtime.h>

typedef float v4f __attribute__((ext_vector_type(4)));

#define N_NODES_C 50000
#define N_EDGES_C 800000
#define NF 128
#define N_GRAPHS_C 256
#define N_CLASSES_C 10

#define SCAN_CHUNK 512
#define SCAN_NB ((N_NODES_C + SCAN_CHUNK - 1) / SCAN_CHUNK)   // 98

// ---------------------------------------------------------------- CSR build
__global__ void k_deg(const int* __restrict__ dst, int* __restrict__ deg) {
  int i = blockIdx.x * blockDim.x + threadIdx.x;
  int stride = gridDim.x * blockDim.x;
  for (; i < N_EDGES_C; i += stride) atomicAdd(&deg[dst[i]], 1);
}

__global__ __launch_bounds__(256) void k_sc1(const int* __restrict__ deg,
                                             float* __restrict__ dinv,
                                             int* __restrict__ bsum) {
  __shared__ int sd[256];
  int b = blockIdx.x, t = threadIdx.x;
  int i0 = b * SCAN_CHUNK + t * 2;
  int e0 = 0, e1 = 0;
  if (i0 < N_NODES_C)     { e0 = deg[i0];     dinv[i0]     = rsqrtf((float)e0 + 1.0f); }
  if (i0 + 1 < N_NODES_C) { e1 = deg[i0 + 1]; dinv[i0 + 1] = rsqrtf((float)e1 + 1.0f); }
  sd[t] = e0 + e1;
  __syncthreads();
  for (int o = 128; o > 0; o >>= 1) {
    if (t < o) sd[t] += sd[t + o];
    __syncthreads();
  }
  if (t == 0) bsum[b] = sd[0];
}

__global__ __launch_bounds__(128) void k_sc2(const int* __restrict__ bsum,
                                             int* __restrict__ boff,
                                             int* __restrict__ ptr) {
  __shared__ int sd[128];
  int t = threadIdx.x;
  int v = (t < SCAN_NB) ? bsum[t] : 0;
  sd[t] = v;
  __syncthreads();
  for (int o = 1; o < 128; o <<= 1) {
    int y = (t >= o) ? sd[t - o] : 0;
    __syncthreads();
    sd[t] += y;
    __syncthreads();
  }
  if (t < SCAN_NB) boff[t] = sd[t] - v;
  if (t == SCAN_NB - 1) ptr[N_NODES_C] = sd[t];
}

__global__ __launch_bounds__(256) void k_sc3(const int* __restrict__ deg,
                                             const int* __restrict__ boff,
                                             int* __restrict__ ptr) {
  __shared__ int sd[256];
  int b = blockIdx.x, t = threadIdx.x;
  int i0 = b * SCAN_CHUNK + t * 2;
  int e0 = (i0 < N_NODES_C) ? deg[i0] : 0;
  int e1 = (i0 + 1 < N_NODES_C) ? deg[i0 + 1] : 0;
  int pair = e0 + e1;
  sd[t] = pair;
  __syncthreads();
  for (int o = 1; o < 256; o <<= 1) {
    int y = (t >= o) ? sd[t - o] : 0;
    __syncthreads();
    sd[t] += y;
    __syncthreads();
  }
  int excl = boff[b] + sd[t] - pair;
  if (i0 < N_NODES_C)     ptr[i0] = excl;
  if (i0 + 1 < N_NODES_C) ptr[i0 + 1] = excl + e0;
}

__global__ void k_fill(const int* __restrict__ src, const int* __restrict__ dst,
                       const int* __restrict__ ptr, int* __restrict__ fill,
                       int* __restrict__ csr_src) {
  int i = blockIdx.x * blockDim.x + threadIdx.x;
  int stride = gridDim.x * blockDim.x;
  for (; i < N_EDGES_C; i += stride) {
    int d = dst[i];
    int pos = atomicAdd(&fill[d], 1);
    csr_src[ptr[d] + pos] = src[i];
  }
}

// ---------------------------------------------------------------- GEMM (fp32, proven R8 structure)
// Tile 64 rows, 256 threads, thread = 4 rows x 8 cols. LDS 68KB -> 2 blk/CU.
// H rows padded to 33 f4 (conflict-free); W skewed cf'=cf+(cf>>3), 2-way reads.
// mode 0: A@W   mode 1: relu(A@W+bias)   mode 2: (A@W)*dinv[row]
#define TN 64
#define HS4 33
#define WS4 35
__global__ __launch_bounds__(256) void k_gemm(const float* __restrict__ A,
    const float* __restrict__ W, const float* __restrict__ bias,
    const float* __restrict__ dinv, float* __restrict__ out, int n, int mode) {
  __shared__ v4f Hl4[TN * HS4];   // 33792 B
  __shared__ v4f Wl4[64 * WS4];   // 35840 B
  int t = threadIdx.x;
  int oq = t & 15;          // output col group: cols oq*8 .. oq*8+7
  int ng = t >> 4;          // 0..15: rows ng, ng+16, ng+32, ng+48
  int woff0 = 2 * oq + ((2 * oq) >> 3);   // skewed W f4 offset
  int nchunks = (n + TN - 1) / TN;
  for (int chunk = blockIdx.x; chunk < nchunks; chunk += gridDim.x) {
    int n0 = chunk * TN;
    __syncthreads();
    {
      const v4f* A4 = (const v4f*)A;
      #pragma unroll
      for (int i = 0; i < 8; ++i) {
        int idx = t + i * 256;              // 0..2047
        int row = idx >> 5, col = idx & 31;
        Hl4[row * HS4 + col] =
            (n0 + row < n) ? A4[(size_t)(n0 + row) * 32 + col] : (v4f)0.0f;
      }
    }
    v4f acc0[4], acc1[4];
    #pragma unroll
    for (int j = 0; j < 4; ++j) { acc0[j] = (v4f)0.0f; acc1[j] = (v4f)0.0f; }
    #pragma unroll 1
    for (int half = 0; half < 2; ++half) {
      int kk4 = half << 4;    // f4 col offset into H (k dim)
      __syncthreads();
      {
        const v4f* W4 = (const v4f*)(W + (size_t)(half << 6) * 128);
        #pragma unroll
        for (int i = 0; i < 8; ++i) {
          int idx = t + i * 256;            // 0..2047
          int r = idx >> 5, cf = idx & 31;
          Wl4[r * WS4 + cf + (cf >> 3)] = W4[r * 32 + cf];
        }
      }
      __syncthreads();
      #pragma unroll 4
      for (int k4 = 0; k4 < 16; ++k4) {
        v4f hA = Hl4[(ng +  0) * HS4 + kk4 + k4];
        v4f hB = Hl4[(ng + 16) * HS4 + kk4 + k4];
        v4f hC = Hl4[(ng + 32) * HS4 + kk4 + k4];
        v4f hD = Hl4[(ng + 48) * HS4 + kk4 + k4];
        #pragma unroll
        for (int u = 0; u < 4; ++u) {
          int rr = k4 * 4 + u;
          v4f w0 = Wl4[rr * WS4 + woff0];
          v4f w1 = Wl4[rr * WS4 + woff0 + 1];
          acc0[0] += hA[u] * w0; acc1[0] += hA[u] * w1;
          acc0[1] += hB[u] * w0; acc1[1] += hB[u] * w1;
          acc0[2] += hC[u] * w0; acc1[2] += hC[u] * w1;
          acc0[3] += hD[u] * w0; acc1[3] += hD[u] * w1;
        }
      }
    }
    v4f b0 = (v4f)0.0f, b1 = (v4f)0.0f;
    if (mode == 1) { b0 = ((const v4f*)bias)[oq * 2]; b1 = ((const v4f*)bias)[oq * 2 + 1]; }
    #pragma unroll
    for (int j = 0; j < 4; ++j) {
      int row = n0 + ng + 16 * j;
      if (row < n) {
        v4f r0 = acc0[j], r1 = acc1[j];
        if (mode == 1) {
          r0 += b0; r1 += b1;
          #pragma unroll
          for (int c = 0; c < 4; ++c) { r0[c] = fmaxf(r0[c], 0.0f); r1[c] = fmaxf(r1[c], 0.0f); }
        } else if (mode == 2) {
          float dv = dinv[row];
          r0 *= dv; r1 *= dv;
        }
        *(v4f*)(out + (size_t)row * 128 + oq * 8) = r0;
        *(v4f*)(out + (size_t)row * 128 + oq * 8 + 4) = r1;
      }
    }
  }
}

// ---------------------------------------------------------------- aggregation
// hws = dinv-pre-scaled hw'. h_i = relu(dinv_i*(sum_{j->i} hw'_j + hw'_i) + b) [+h_i]
// fp32 random-gather floor (~61 us full). Split into 2 half-node dispatches
// (diagnostic: exposes k_gemm counters in rocprof top-5; perf-neutral).
__global__ __launch_bounds__(256) void k_agg(const float* __restrict__ hws,
    const int* __restrict__ ptr, const int* __restrict__ csr_src,
    const float* __restrict__ dinv, const float* __restrict__ bias,
    float* __restrict__ h, int residual, int node0, int node_end) {
  int node = node0 + blockIdx.x * 4 + (threadIdx.x >> 6);
  int lane = threadIdx.x & 63;
  int half = lane >> 5;
  int c4 = lane & 31;
  if (node >= node_end) return;
  const v4f* hw4 = (const v4f*)hws;
  int beg = ptr[node], end = ptr[node + 1];
  v4f acc = (v4f)0.0f;
  int e = beg;
  for (; e + 16 <= end; e += 16) {
    int s0 = csr_src[e +  0 + half], s1 = csr_src[e +  2 + half];
    int s2 = csr_src[e +  4 + half], s3 = csr_src[e +  6 + half];
    int s4 = csr_src[e +  8 + half], s5 = csr_src[e + 10 + half];
    int s6 = csr_src[e + 12 + half], s7 = csr_src[e + 14 + half];
    v4f v0 = hw4[(size_t)s0 * 32 + c4];
    v4f v1 = hw4[(size_t)s1 * 32 + c4];
    v4f v2 = hw4[(size_t)s2 * 32 + c4];
    v4f v3 = hw4[(size_t)s3 * 32 + c4];
    v4f v4 = hw4[(size_t)s4 * 32 + c4];
    v4f v5 = hw4[(size_t)s5 * 32 + c4];
    v4f v6 = hw4[(size_t)s6 * 32 + c4];
    v4f v7 = hw4[(size_t)s7 * 32 + c4];
    acc += v0; acc += v1; acc += v2; acc += v3;
    acc += v4; acc += v5; acc += v6; acc += v7;
  }
  for (; e + 8 <= end; e += 8) {
    int s0 = csr_src[e + half],     s1 = csr_src[e + 2 + half];
    int s2 = csr_src[e + 4 + half], s3 = csr_src[e + 6 + half];
    v4f v0 = hw4[(size_t)s0 * 32 + c4];
    v4f v1 = hw4[(size_t)s1 * 32 + c4];
    v4f v2 = hw4[(size_t)s2 * 32 + c4];
    v4f v3 = hw4[(size_t)s3 * 32 + c4];
    acc += v0; acc += v1; acc += v2; acc += v3;
  }
  for (; e < end; e += 2) {
    int idx = e + half;
    if (idx < end) acc += hw4[(size_t)csr_src[idx] * 32 + c4];
  }
  v4f tot;
  #pragma unroll
  for (int c = 0; c < 4; ++c) tot[c] = acc[c] + __shfl_xor(acc[c], 32);

  float di = dinv[node];
  v4f selfv = hw4[(size_t)node * 32 + c4];
  v4f b = ((const v4f*)bias)[c4];
  v4f r = di * (tot + selfv) + b;
  #pragma unroll
  for (int c = 0; c < 4; ++c) r[c] = fmaxf(r[c], 0.0f);
  v4f* h4 = (v4f*)h;
  if (residual) r += h4[(size_t)node * 32 + c4];
  if (half == 0) h4[(size_t)node * 32 + c4] = r;
}

// ---------------------------------------------------------------- fused pool + head
// Block per graph (128 threads): binary-search bounds, mean-pool, 2-layer head.
__global__ __launch_bounds__(128) void k_poolhead(const float* __restrict__ h,
    const int* __restrict__ batch, const float* __restrict__ Wc1,
    const float* __restrict__ bc1, const float* __restrict__ Wc2,
    const float* __restrict__ bc2, float* __restrict__ out) {
  __shared__ float gv[128];
  __shared__ float hid[64];
  __shared__ int bounds[2];
  int g = blockIdx.x, t = threadIdx.x;
  if (t < 2) {
    int target = g + t;
    int lo = 0, hi = N_NODES_C;
    while (lo < hi) {
      int mid = (lo + hi) >> 1;
      if (batch[mid] < target) lo = mid + 1; else hi = mid;
    }
    bounds[t] = lo;
  }
  __syncthreads();
  int beg = bounds[0], end = bounds[1];
  float acc = 0.f;
  for (int n2 = beg; n2 < end; ++n2) acc += h[(size_t)n2 * NF + t];
  gv[t] = acc / fmaxf((float)(end - beg), 1.0f);
  __syncthreads();
  if (t < 64) {
    float s = bc1[t];
    #pragma unroll 8
    for (int k = 0; k < 128; ++k) s += gv[k] * Wc1[k * 64 + t];
    hid[t] = fmaxf(s, 0.0f);
  }
  __syncthreads();
  if (t < N_CLASSES_C) {
    float o = bc2[t];
    #pragma unroll
    for (int k = 0; k < 64; ++k) o += hid[k] * Wc2[k * 10 + t];
    out[g * 10 + t] = o;
  }
}

// ---------------------------------------------------------------- launch
extern "C" void kernel_launch(void* const* d_in, const int* in_sizes, int n_in,
                              void* d_out, int out_size, void* d_ws, size_t ws_size,
                              hipStream_t stream) {
  const float* x    = (const float*)d_in[0];
  const int*   ei   = (const int*)d_in[1];
  const int*   batch= (const int*)d_in[2];
  const float* W_in = (const float*)d_in[3];
  const float* b_in = (const float*)d_in[4];
  const float* Ws   = (const float*)d_in[5];
  const float* bs   = (const float*)d_in[6];
  const float* Wc1  = (const float*)d_in[7];
  const float* bc1  = (const float*)d_in[8];
  const float* Wc2  = (const float*)d_in[9];
  const float* bc2  = (const float*)d_in[10];
  float* out = (float*)d_out;

  const int* src = ei;
  const int* dst = ei + N_EDGES_C;

  char* ws = (char*)d_ws;
  size_t off = 0;
  auto alloc = [&](size_t bytes) -> void* {
    void* p = ws + off;
    off += (bytes + 255) & ~(size_t)255;
    return p;
  };
  int*   deg     = (int*)alloc(N_NODES_C * 4);
  int*   fill    = (int*)alloc(N_NODES_C * 4);
  int*   csr_ptr = (int*)alloc((N_NODES_C + 1) * 4);
  int*   csr_src = (int*)alloc((size_t)N_EDGES_C * 4);
  float* dinv    = (float*)alloc(N_NODES_C * 4);
  int*   bsum    = (int*)alloc(SCAN_NB * 4);
  int*   boff    = (int*)alloc(SCAN_NB * 4);
  float* h       = (float*)alloc((size_t)N_NODES_C * NF * 4);
  float* hw      = (float*)alloc((size_t)N_NODES_C * NF * 4);
  (void)ws_size; (void)in_sizes; (void)n_in; (void)out_size;

  hipMemsetAsync(deg, 0, N_NODES_C * 4, stream);
  hipMemsetAsync(fill, 0, N_NODES_C * 4, stream);

  k_deg<<<1024, 256, 0, stream>>>(dst, deg);
  k_sc1<<<SCAN_NB, 256, 0, stream>>>(deg, dinv, bsum);
  k_sc2<<<1, 128, 0, stream>>>(bsum, boff, csr_ptr);
  k_sc3<<<SCAN_NB, 256, 0, stream>>>(deg, boff, csr_ptr);
  k_fill<<<1024, 256, 0, stream>>>(src, dst, csr_ptr, fill, csr_src);

  // input layer: h = relu(x @ W_in + b_in)
  k_gemm<<<512, 256, 0, stream>>>(x, W_in, b_in, nullptr, h, N_NODES_C, 1);

  const int HALF_N = N_NODES_C / 2;   // 25000
  for (int L = 0; L < 3; ++L) {
    // hw' = (h @ Ws[L]) * dinv  (pre-scaled for aggregation)
    k_gemm<<<512, 256, 0, stream>>>(h, Ws + (size_t)L * NF * NF, nullptr, dinv,
                                    hw, N_NODES_C, 2);
    k_agg<<<(HALF_N + 3) / 4, 256, 0, stream>>>(hw, csr_ptr, csr_src, dinv,
                                                bs + (size_t)L * NF, h, (L > 0) ? 1 : 0,
                                                0, HALF_N);
    k_agg<<<(N_NODES_C - HALF_N + 3) / 4, 256, 0, stream>>>(hw, csr_ptr, csr_src, dinv,
                                                bs + (size_t)L * NF, h, (L > 0) ? 1 : 0,
                                                HALF_N, N_NODES_C);
  }

  k_poolhead<<<N_GRAPHS_C, 128, 0, stream>>>(h, batch, Wc1, bc1, Wc2, bc2, out);
}

// Round 17
// 529.831 us; speedup vs baseline: 1.1315x; 1.0725x over previous
//
#include <hip/hip_runtime.h>

typedef float v4f __attribute__((ext_vector_type(4)));

#define N_NODES_C 50000
#define N_EDGES_C 800000
#define NF 128
#define N_GRAPHS_C 256
#define N_CLASSES_C 10

#define SCAN_CHUNK 512
#define SCAN_NB ((N_NODES_C + SCAN_CHUNK - 1) / SCAN_CHUNK)   // 98

// ---------------------------------------------------------------- CSR build
__global__ void k_deg(const int* __restrict__ dst, int* __restrict__ deg) {
  int i = blockIdx.x * blockDim.x + threadIdx.x;
  int stride = gridDim.x * blockDim.x;
  for (; i < N_EDGES_C; i += stride) atomicAdd(&deg[dst[i]], 1);
}

__global__ __launch_bounds__(256) void k_sc1(const int* __restrict__ deg,
                                             float* __restrict__ dinv,
                                             int* __restrict__ bsum) {
  __shared__ int sd[256];
  int b = blockIdx.x, t = threadIdx.x;
  int i0 = b * SCAN_CHUNK + t * 2;
  int e0 = 0, e1 = 0;
  if (i0 < N_NODES_C)     { e0 = deg[i0];     dinv[i0]     = rsqrtf((float)e0 + 1.0f); }
  if (i0 + 1 < N_NODES_C) { e1 = deg[i0 + 1]; dinv[i0 + 1] = rsqrtf((float)e1 + 1.0f); }
  sd[t] = e0 + e1;
  __syncthreads();
  for (int o = 128; o > 0; o >>= 1) {
    if (t < o) sd[t] += sd[t + o];
    __syncthreads();
  }
  if (t == 0) bsum[b] = sd[0];
}

__global__ __launch_bounds__(128) void k_sc2(const int* __restrict__ bsum,
                                             int* __restrict__ boff,
                                             int* __restrict__ ptr) {
  __shared__ int sd[128];
  int t = threadIdx.x;
  int v = (t < SCAN_NB) ? bsum[t] : 0;
  sd[t] = v;
  __syncthreads();
  for (int o = 1; o < 128; o <<= 1) {
    int y = (t >= o) ? sd[t - o] : 0;
    __syncthreads();
    sd[t] += y;
    __syncthreads();
  }
  if (t < SCAN_NB) boff[t] = sd[t] - v;
  if (t == SCAN_NB - 1) ptr[N_NODES_C] = sd[t];
}

__global__ __launch_bounds__(256) void k_sc3(const int* __restrict__ deg,
                                             const int* __restrict__ boff,
                                             int* __restrict__ ptr) {
  __shared__ int sd[256];
  int b = blockIdx.x, t = threadIdx.x;
  int i0 = b * SCAN_CHUNK + t * 2;
  int e0 = (i0 < N_NODES_C) ? deg[i0] : 0;
  int e1 = (i0 + 1 < N_NODES_C) ? deg[i0 + 1] : 0;
  int pair = e0 + e1;
  sd[t] = pair;
  __syncthreads();
  for (int o = 1; o < 256; o <<= 1) {
    int y = (t >= o) ? sd[t - o] : 0;
    __syncthreads();
    sd[t] += y;
    __syncthreads();
  }
  int excl = boff[b] + sd[t] - pair;
  if (i0 < N_NODES_C)     ptr[i0] = excl;
  if (i0 + 1 < N_NODES_C) ptr[i0 + 1] = excl + e0;
}

__global__ void k_fill(const int* __restrict__ src, const int* __restrict__ dst,
                       const int* __restrict__ ptr, int* __restrict__ fill,
                       int* __restrict__ csr_src) {
  int i = blockIdx.x * blockDim.x + threadIdx.x;
  int stride = gridDim.x * blockDim.x;
  for (; i < N_EDGES_C; i += stride) {
    int d = dst[i];
    int pos = atomicAdd(&fill[d], 1);
    csr_src[ptr[d] + pos] = src[i];
  }
}

// ---------------------------------------------------------------- GEMM (fp32, proven R8 structure)
// Tile 64 rows, 256 threads, thread = 4 rows x 8 cols. LDS 68KB -> 2 blk/CU.
// H rows padded to 33 f4 (conflict-free); W skewed cf'=cf+(cf>>3), 2-way reads.
// mode 0: A@W   mode 1: relu(A@W+bias)   mode 2: (A@W)*dinv[row]
#define TN 64
#define HS4 33
#define WS4 35
__global__ __launch_bounds__(256) void k_gemm(const float* __restrict__ A,
    const float* __restrict__ W, const float* __restrict__ bias,
    const float* __restrict__ dinv, float* __restrict__ out, int n, int mode) {
  __shared__ v4f Hl4[TN * HS4];   // 33792 B
  __shared__ v4f Wl4[64 * WS4];   // 35840 B
  int t = threadIdx.x;
  int oq = t & 15;          // output col group: cols oq*8 .. oq*8+7
  int ng = t >> 4;          // 0..15: rows ng, ng+16, ng+32, ng+48
  int woff0 = 2 * oq + ((2 * oq) >> 3);   // skewed W f4 offset
  int nchunks = (n + TN - 1) / TN;
  for (int chunk = blockIdx.x; chunk < nchunks; chunk += gridDim.x) {
    int n0 = chunk * TN;
    __syncthreads();
    {
      const v4f* A4 = (const v4f*)A;
      #pragma unroll
      for (int i = 0; i < 8; ++i) {
        int idx = t + i * 256;              // 0..2047
        int row = idx >> 5, col = idx & 31;
        Hl4[row * HS4 + col] =
            (n0 + row < n) ? A4[(size_t)(n0 + row) * 32 + col] : (v4f)0.0f;
      }
    }
    v4f acc0[4], acc1[4];
    #pragma unroll
    for (int j = 0; j < 4; ++j) { acc0[j] = (v4f)0.0f; acc1[j] = (v4f)0.0f; }
    #pragma unroll 1
    for (int half = 0; half < 2; ++half) {
      int kk4 = half << 4;    // f4 col offset into H (k dim)
      __syncthreads();
      {
        const v4f* W4 = (const v4f*)(W + (size_t)(half << 6) * 128);
        #pragma unroll
        for (int i = 0; i < 8; ++i) {
          int idx = t + i * 256;            // 0..2047
          int r = idx >> 5, cf = idx & 31;
          Wl4[r * WS4 + cf + (cf >> 3)] = W4[r * 32 + cf];
        }
      }
      __syncthreads();
      #pragma unroll 4
      for (int k4 = 0; k4 < 16; ++k4) {
        v4f hA = Hl4[(ng +  0) * HS4 + kk4 + k4];
        v4f hB = Hl4[(ng + 16) * HS4 + kk4 + k4];
        v4f hC = Hl4[(ng + 32) * HS4 + kk4 + k4];
        v4f hD = Hl4[(ng + 48) * HS4 + kk4 + k4];
        #pragma unroll
        for (int u = 0; u < 4; ++u) {
          int rr = k4 * 4 + u;
          v4f w0 = Wl4[rr * WS4 + woff0];
          v4f w1 = Wl4[rr * WS4 + woff0 + 1];
          acc0[0] += hA[u] * w0; acc1[0] += hA[u] * w1;
          acc0[1] += hB[u] * w0; acc1[1] += hB[u] * w1;
          acc0[2] += hC[u] * w0; acc1[2] += hC[u] * w1;
          acc0[3] += hD[u] * w0; acc1[3] += hD[u] * w1;
        }
      }
    }
    v4f b0 = (v4f)0.0f, b1 = (v4f)0.0f;
    if (mode == 1) { b0 = ((const v4f*)bias)[oq * 2]; b1 = ((const v4f*)bias)[oq * 2 + 1]; }
    #pragma unroll
    for (int j = 0; j < 4; ++j) {
      int row = n0 + ng + 16 * j;
      if (row < n) {
        v4f r0 = acc0[j], r1 = acc1[j];
        if (mode == 1) {
          r0 += b0; r1 += b1;
          #pragma unroll
          for (int c = 0; c < 4; ++c) { r0[c] = fmaxf(r0[c], 0.0f); r1[c] = fmaxf(r1[c], 0.0f); }
        } else if (mode == 2) {
          float dv = dinv[row];
          r0 *= dv; r1 *= dv;
        }
        *(v4f*)(out + (size_t)row * 128 + oq * 8) = r0;
        *(v4f*)(out + (size_t)row * 128 + oq * 8 + 4) = r1;
      }
    }
  }
}

// ---------------------------------------------------------------- aggregation
// hws = dinv-pre-scaled hw'. h_i = relu(dinv_i*(sum_{j->i} hw'_j + hw'_i) + b) [+h_i]
// fp32 random-gather floor (~31 us per half). Split into 2 half-node dispatches
// (keeps k_gemm visible in rocprof top-5).
__global__ __launch_bounds__(256) void k_agg(const float* __restrict__ hws,
    const int* __restrict__ ptr, const int* __restrict__ csr_src,
    const float* __restrict__ dinv, const float* __restrict__ bias,
    float* __restrict__ h, int residual, int node0, int node_end) {
  int node = node0 + blockIdx.x * 4 + (threadIdx.x >> 6);
  int lane = threadIdx.x & 63;
  int half = lane >> 5;
  int c4 = lane & 31;
  if (node >= node_end) return;
  const v4f* hw4 = (const v4f*)hws;
  int beg = ptr[node], end = ptr[node + 1];
  v4f acc = (v4f)0.0f;
  int e = beg;
  for (; e + 16 <= end; e += 16) {
    int s0 = csr_src[e +  0 + half], s1 = csr_src[e +  2 + half];
    int s2 = csr_src[e +  4 + half], s3 = csr_src[e +  6 + half];
    int s4 = csr_src[e +  8 + half], s5 = csr_src[e + 10 + half];
    int s6 = csr_src[e + 12 + half], s7 = csr_src[e + 14 + half];
    v4f v0 = hw4[(size_t)s0 * 32 + c4];
    v4f v1 = hw4[(size_t)s1 * 32 + c4];
    v4f v2 = hw4[(size_t)s2 * 32 + c4];
    v4f v3 = hw4[(size_t)s3 * 32 + c4];
    v4f v4 = hw4[(size_t)s4 * 32 + c4];
    v4f v5 = hw4[(size_t)s5 * 32 + c4];
    v4f v6 = hw4[(size_t)s6 * 32 + c4];
    v4f v7 = hw4[(size_t)s7 * 32 + c4];
    acc += v0; acc += v1; acc += v2; acc += v3;
    acc += v4; acc += v5; acc += v6; acc += v7;
  }
  for (; e + 8 <= end; e += 8) {
    int s0 = csr_src[e + half],     s1 = csr_src[e + 2 + half];
    int s2 = csr_src[e + 4 + half], s3 = csr_src[e + 6 + half];
    v4f v0 = hw4[(size_t)s0 * 32 + c4];
    v4f v1 = hw4[(size_t)s1 * 32 + c4];
    v4f v2 = hw4[(size_t)s2 * 32 + c4];
    v4f v3 = hw4[(size_t)s3 * 32 + c4];
    acc += v0; acc += v1; acc += v2; acc += v3;
  }
  for (; e < end; e += 2) {
    int idx = e + half;
    if (idx < end) acc += hw4[(size_t)csr_src[idx] * 32 + c4];
  }
  v4f tot;
  #pragma unroll
  for (int c = 0; c < 4; ++c) tot[c] = acc[c] + __shfl_xor(acc[c], 32);

  float di = dinv[node];
  v4f selfv = hw4[(size_t)node * 32 + c4];
  v4f b = ((const v4f*)bias)[c4];
  v4f r = di * (tot + selfv) + b;
  #pragma unroll
  for (int c = 0; c < 4; ++c) r[c] = fmaxf(r[c], 0.0f);
  v4f* h4 = (v4f*)h;
  if (residual) r += h4[(size_t)node * 32 + c4];
  if (half == 0) h4[(size_t)node * 32 + c4] = r;
}

// ---------------------------------------------------------------- fused pool + head
// Block per graph, 1024 threads = 8 row-lanes x 128 features.
// 8 concurrent node-row streams per block (16 waves/CU vs old 2) hide latency.
__global__ __launch_bounds__(1024) void k_poolhead(const float* __restrict__ h,
    const int* __restrict__ batch, const float* __restrict__ Wc1,
    const float* __restrict__ bc1, const float* __restrict__ Wc2,
    const float* __restrict__ bc2, float* __restrict__ out) {
  __shared__ float partial[8][128];
  __shared__ float gv[128];
  __shared__ float hid[64];
  __shared__ int bounds[2];
  int g = blockIdx.x, t = threadIdx.x;
  int f = t & 127, row = t >> 7;       // row 0..7
  if (t < 2) {
    int target = g + t;
    int lo = 0, hi = N_NODES_C;
    while (lo < hi) {
      int mid = (lo + hi) >> 1;
      if (batch[mid] < target) lo = mid + 1; else hi = mid;
    }
    bounds[t] = lo;
  }
  __syncthreads();
  int beg = bounds[0], end = bounds[1];
  float acc = 0.f;
  for (int n2 = beg + row; n2 < end; n2 += 8) acc += h[(size_t)n2 * NF + f];
  partial[row][f] = acc;
  __syncthreads();
  if (t < 128) {
    float s = partial[0][t];
    #pragma unroll
    for (int r = 1; r < 8; ++r) s += partial[r][t];
    gv[t] = s / fmaxf((float)(end - beg), 1.0f);
  }
  __syncthreads();
  if (t < 64) {
    float s = bc1[t];
    #pragma unroll 8
    for (int k = 0; k < 128; ++k) s += gv[k] * Wc1[k * 64 + t];
    hid[t] = fmaxf(s, 0.0f);
  }
  __syncthreads();
  if (t < N_CLASSES_C) {
    float o = bc2[t];
    #pragma unroll
    for (int k = 0; k < 64; ++k) o += hid[k] * Wc2[k * 10 + t];
    out[g * 10 + t] = o;
  }
}

// ---------------------------------------------------------------- launch
extern "C" void kernel_launch(void* const* d_in, const int* in_sizes, int n_in,
                              void* d_out, int out_size, void* d_ws, size_t ws_size,
                              hipStream_t stream) {
  const float* x    = (const float*)d_in[0];
  const int*   ei   = (const int*)d_in[1];
  const int*   batch= (const int*)d_in[2];
  const float* W_in = (const float*)d_in[3];
  const float* b_in = (const float*)d_in[4];
  const float* Ws   = (const float*)d_in[5];
  const float* bs   = (const float*)d_in[6];
  const float* Wc1  = (const float*)d_in[7];
  const float* bc1  = (const float*)d_in[8];
  const float* Wc2  = (const float*)d_in[9];
  const float* bc2  = (const float*)d_in[10];
  float* out = (float*)d_out;

  const int* src = ei;
  const int* dst = ei + N_EDGES_C;

  char* ws = (char*)d_ws;
  size_t off = 0;
  auto alloc = [&](size_t bytes) -> void* {
    void* p = ws + off;
    off += (bytes + 255) & ~(size_t)255;
    return p;
  };
  int*   deg     = (int*)alloc(N_NODES_C * 4);
  int*   fill    = (int*)alloc(N_NODES_C * 4);
  int*   csr_ptr = (int*)alloc((N_NODES_C + 1) * 4);
  int*   csr_src = (int*)alloc((size_t)N_EDGES_C * 4);
  float* dinv    = (float*)alloc(N_NODES_C * 4);
  int*   bsum    = (int*)alloc(SCAN_NB * 4);
  int*   boff    = (int*)alloc(SCAN_NB * 4);
  float* h       = (float*)alloc((size_t)N_NODES_C * NF * 4);
  float* hw      = (float*)alloc((size_t)N_NODES_C * NF * 4);
  (void)ws_size; (void)in_sizes; (void)n_in; (void)out_size;

  hipMemsetAsync(deg, 0, N_NODES_C * 4, stream);
  hipMemsetAsync(fill, 0, N_NODES_C * 4, stream);

  k_deg<<<1024, 256, 0, stream>>>(dst, deg);
  k_sc1<<<SCAN_NB, 256, 0, stream>>>(deg, dinv, bsum);
  k_sc2<<<1, 128, 0, stream>>>(bsum, boff, csr_ptr);
  k_sc3<<<SCAN_NB, 256, 0, stream>>>(deg, boff, csr_ptr);
  k_fill<<<1024, 256, 0, stream>>>(src, dst, csr_ptr, fill, csr_src);

  // input layer: h = relu(x @ W_in + b_in)
  k_gemm<<<512, 256, 0, stream>>>(x, W_in, b_in, nullptr, h, N_NODES_C, 1);

  const int HALF_N = N_NODES_C / 2;   // 25000
  for (int L = 0; L < 3; ++L) {
    // hw' = (h @ Ws[L]) * dinv  (pre-scaled for aggregation)
    k_gemm<<<512, 256, 0, stream>>>(h, Ws + (size_t)L * NF * NF, nullptr, dinv,
                                    hw, N_NODES_C, 2);
    k_agg<<<(HALF_N + 3) / 4, 256, 0, stream>>>(hw, csr_ptr, csr_src, dinv,
                                                bs + (size_t)L * NF, h, (L > 0) ? 1 : 0,
                                                0, HALF_N);
    k_agg<<<(N_NODES_C - HALF_N + 3) / 4, 256, 0, stream>>>(hw, csr_ptr, csr_src, dinv,
                                                bs + (size_t)L * NF, h, (L > 0) ? 1 : 0,
                                                HALF_N, N_NODES_C);
  }

  k_poolhead<<<N_GRAPHS_C, 1024, 0, stream>>>(h, batch, Wc1, bc1, Wc2, bc2, out);
}